// Round 7
// baseline (295.124 us; speedup 1.0000x reference)
//
#include <hip/hip_runtime.h>
#include <stdint.h>

// Problem constants (from reference):
constexpr int kB   = 8;
constexpr int kL1  = 1024;
constexpr int kC   = 128;
constexpr int kL2  = 256;
constexpr int kS   = 16;
constexpr int kNQ  = kB * kS;        // 128 queries
constexpr int kNDB = 8192;
constexpr float kEPS = 1e-8f;
constexpr int kRow = kC * kL2;       // 32768 floats per database row

constexpr int kCCh   = 32;           // c-values per chunk -> 32 KB CONTIGUOUS
constexpr int kChF   = kCCh * kL2;   // 8192 floats per chunk
constexpr int kPitch = 33;           // LDS tile pitch: [row(l2)][c'] padded
constexpr int kTileF = 256 * kPitch; // 8448 floats (33,792 B)
constexpr int kZeroIdx = kTileF - 1; // 8447: pad slot, never written by data
constexpr int kCap   = 128;          // bucket capacity: TRUE worst case
                                     // (256 dup-c entries, h-parity split)
constexpr uint16_t kZeroOff = (uint16_t)(kZeroIdx * 4);  // 33788 (byte)
constexpr int kQB    = 2 * 4 * kCap; // u16 per q in bucket table (1024)

// Raw barrier: LDS visibility via lgkmcnt(0), NO vmcnt drain -- global loads
// stay in flight across it (T4 pattern, proven rounds 4-5).
#define BARRIER_LG()                                          \
    do {                                                      \
        asm volatile("s_waitcnt lgkmcnt(0)" ::: "memory");    \
        __builtin_amdgcn_s_barrier();                         \
        asm volatile("" ::: "memory");                        \
    } while (0)

// ---------------------------------------------------------------------------
// Phase 0: bucketed gather-address table + counts. One block per q.
// Entry for (q,l2): c = seq[b][clip(trunc(pos))]; chunk = c>>5;
//   LDS byte offset = (row(l2)*33 + (c&31))*4, row(l2)=((l2&3)<<6)|(l2>>2).
// Deterministic bucketing: rank entries of each chunk by l2 (ballot+popc
// within wave + wave-count prefix), h = rank&1, slot = rank>>1 (<=127).
// cnts[(q*2+h)*4+ch] = (total_ch + 1 - h) >> 1. Pads -> kZeroOff (reads 0.0).
// pos = f32(start) + f32(end-start)*((l2+0.5)/256) -- mul then add, NO fma.
// ---------------------------------------------------------------------------
__global__ void build_addr_kernel(const int* __restrict__ seq,
                                  const int* __restrict__ kp,
                                  uint16_t* __restrict__ bkt,
                                  uint16_t* __restrict__ cnts) {
    __shared__ int wcnt[4][4];    // [wave][chunk]
    const int q  = blockIdx.x;    // 0..127
    const int l2 = threadIdx.x;   // 0..255
    const int b = q >> 4;
    const int s = q & 15;
    int start = kp[b * (kS + 1) + s];
    int end_  = kp[b * (kS + 1) + s + 1];
    if (end_ < start + 1) end_ = start + 1;
    const float frac = (l2 + 0.5f) * (1.0f / 256.0f);   // exact (pow2 divide)
    const float pos = __fadd_rn((float)start, __fmul_rn((float)(end_ - start), frac));
    int idx = (int)pos;                                  // trunc, pos >= 0
    idx = idx < 0 ? 0 : (idx > kL1 - 1 ? kL1 - 1 : idx);
    const int c = seq[b * kL1 + idx];

    const int ch  = c >> 5;
    const int row = ((l2 & 3) << 6) | (l2 >> 2);
    const uint16_t off = (uint16_t)((row * kPitch + (c & 31)) * 4);

    // pad-init this q's bucket region (1024 entries)
    uint16_t* qb = bkt + (size_t)q * kQB;
    #pragma unroll
    for (int i = 0; i < 4; ++i) qb[l2 + 256 * i] = kZeroOff;

    const int wave = l2 >> 6, lane = l2 & 63;
    const uint64_t m0 = __ballot(ch == 0);
    const uint64_t m1 = __ballot(ch == 1);
    const uint64_t m2 = __ballot(ch == 2);
    const uint64_t m3 = __ballot(ch == 3);
    const uint64_t below = (lane == 63) ? 0x7fffffffffffffffull
                                        : (((uint64_t)1 << lane) - 1);
    const uint64_t mym = ch == 0 ? m0 : ch == 1 ? m1 : ch == 2 ? m2 : m3;
    int r = (int)__popcll(mym & below);
    if (lane < 4)
        wcnt[wave][lane] = (int)__popcll(lane == 0 ? m0 : lane == 1 ? m1
                                       : lane == 2 ? m2 : m3);
    __syncthreads();   // publishes wcnt AND orders pad stores before scatter
    #pragma unroll
    for (int w = 0; w < 3; ++w)
        if (wave > w) r += wcnt[w][ch];
    const int h = r & 1, slot = r >> 1;          // slot <= 127 always
    qb[(h * 4 + ch) * kCap + slot] = off;

    if (l2 < 8) {                                 // counts: h=l2&1, ch=l2>>1
        const int hh = l2 & 1, cc = l2 >> 1;
        const int total = wcnt[0][cc] + wcnt[1][cc] + wcnt[2][cc] + wcnt[3][cc];
        cnts[(q * 2 + hh) * 4 + cc] = (uint16_t)((total + 1 - hh) >> 1);
    }
}

// ---------------------------------------------------------------------------
// Producer helpers. Chunk = 32 KB contiguous; thread t covers float4 at
// chunk_base + (t+256k)*4, k=0..7 -> block streams the row strictly forward.
// LDS write: fi=t+256k, c'=fi>>6, m=fi&63; element r of the float4 has
// l2 = 4m+r -> row = (r<<6)|m -> off = m*33 + c' + r*2112.
// Per wave-instr banks: (lane + c') & 31 -> 2 lanes/bank: FREE.
// ---------------------------------------------------------------------------
__device__ __forceinline__ void stage_load(const float* __restrict__ rowp,
                                           int chunk, float4 (&buf)[8], int t) {
    const float* base = rowp + chunk * kChF;
    #pragma unroll
    for (int k = 0; k < 8; ++k)
        buf[k] = *reinterpret_cast<const float4*>(base + (t + 256 * k) * 4);
}

__device__ __forceinline__ void stage_write(float* tile, const float4 (&buf)[8],
                                            int t, float& nrm) {
    #pragma unroll
    for (int k = 0; k < 8; ++k) {
        const int fi = t + 256 * k;
        const int cc = fi >> 6;
        const int m  = fi & 63;
        const int o  = m * kPitch + cc;
        const float4 v = buf[k];
        nrm = fmaf(v.x, v.x, nrm);
        nrm = fmaf(v.y, v.y, nrm);
        nrm = fmaf(v.z, v.z, nrm);
        nrm = fmaf(v.w, v.w, nrm);
        tile[o +    0] = v.x;     //  64*33 = 2112
        tile[o + 2112] = v.y;
        tile[o + 4224] = v.z;
        tile[o + 6336] = v.w;
    }
}

// Consumer: dynamic-length bucket gather (trips = ceil(cnt/8), <= 16).
__device__ __forceinline__ void gatherN(const float* tile,
                                        const uint4* __restrict__ bp, int trips,
                                        float& a0, float& a1, float& a2, float& a3) {
    const char* tb = (const char*)tile;
    for (int g = 0; g < trips; ++g) {
        union { uint4 v; uint16_t u[8]; } pk;
        pk.v = bp[g];
        a0 += *(const float*)(tb + pk.u[0]);
        a1 += *(const float*)(tb + pk.u[1]);
        a2 += *(const float*)(tb + pk.u[2]);
        a3 += *(const float*)(tb + pk.u[3]);
        a0 += *(const float*)(tb + pk.u[4]);
        a1 += *(const float*)(tb + pk.u[5]);
        a2 += *(const float*)(tb + pk.u[6]);
        a3 += *(const float*)(tb + pk.u[7]);
    }
}

// ---------------------------------------------------------------------------
// Phase 1: one 512-thread block per database row n.
// Waves 0-3: PRODUCERS -- stream 4 contiguous 32KB chunks through regs
//   (fused norm fma) into ping-pong LDS tiles; >=1 chunk of loads always in
//   flight. Waves 4-7: CONSUMERS -- bucketed gathers from the tile filled
//   last phase (count-bounded loops; L2-hot bucket table).
// 5 lgkm-only barriers, both paths (wave-aligned split).
// LDS 68.1 KB -> 2 blocks/CU. launch_bounds(512,2) -> 128 VGPR budget.
// ---------------------------------------------------------------------------
__launch_bounds__(512, 2)
__global__ void sim_kernel(const float* __restrict__ db,
                           const uint16_t* __restrict__ bkt,
                           const uint16_t* __restrict__ cnts,
                           float* __restrict__ sims) {
    __shared__ float tileA[kTileF];   // 33,792 B
    __shared__ float tileB[kTileF];   // 33,792 B
    __shared__ float accbuf[128];
    __shared__ float nsh[4];

    const int n = blockIdx.x;
    const int t = threadIdx.x;
    const float* rowp = db + (size_t)n * kRow;

    if (t < 256) {
        // ================= PRODUCER =================
        if (t == 0) { tileA[kZeroIdx] = 0.f; tileB[kZeroIdx] = 0.f; }
        float4 bufA[8], bufB[8];
        stage_load(rowp, 0, bufA, t);
        stage_load(rowp, 1, bufB, t);
        float nrm = 0.f;

        stage_write(tileA, bufA, t, nrm);   // vmcnt waits only for bufA
        stage_load(rowp, 2, bufA, t);       // refill; flies across barriers
        BARRIER_LG();                       // BAR1: T0 ready

        stage_write(tileB, bufB, t, nrm);
        stage_load(rowp, 3, bufB, t);
        BARRIER_LG();                       // BAR2: T1 ready, T0 drained

        stage_write(tileA, bufA, t, nrm);
        BARRIER_LG();                       // BAR3: T0 ready, T1 drained

        stage_write(tileB, bufB, t, nrm);
        BARRIER_LG();                       // BAR4: T1 ready

        // norm reduce while consumers drain the last tile
        float nw = nrm;
        #pragma unroll
        for (int off = 32; off > 0; off >>= 1) nw += __shfl_down(nw, off);
        if ((t & 63) == 0) nsh[t >> 6] = nw;
        BARRIER_LG();                       // BAR5: nsh + accbuf visible
    } else {
        // ================= CONSUMER =================
        const int u = t - 256;
        const int q = u & 127;
        const int h = u >> 7;

        const ushort4 C4 = *reinterpret_cast<const ushort4*>(
            cnts + (q * 2 + h) * 4);                       // counts ch 0..3
        const uint16_t* qb = bkt + (size_t)q * kQB + (h * 4) * kCap;
        const uint4* bp0 = reinterpret_cast<const uint4*>(qb + 0 * kCap);
        const uint4* bp1 = reinterpret_cast<const uint4*>(qb + 1 * kCap);
        const uint4* bp2 = reinterpret_cast<const uint4*>(qb + 2 * kCap);
        const uint4* bp3 = reinterpret_cast<const uint4*>(qb + 3 * kCap);

        float a0 = 0.f, a1 = 0.f, a2 = 0.f, a3 = 0.f;

        BARRIER_LG();                       // BAR1
        gatherN(tileA, bp0, (C4.x + 7) >> 3, a0, a1, a2, a3);
        BARRIER_LG();                       // BAR2
        gatherN(tileB, bp1, (C4.y + 7) >> 3, a0, a1, a2, a3);
        BARRIER_LG();                       // BAR3
        gatherN(tileA, bp2, (C4.z + 7) >> 3, a0, a1, a2, a3);
        BARRIER_LG();                       // BAR4
        gatherN(tileB, bp3, (C4.w + 7) >> 3, a0, a1, a2, a3);

        const float part = (a0 + a1) + (a2 + a3);
        if (h) accbuf[q] = part;
        BARRIER_LG();                       // BAR5

        if (!h) {
            const float total = part + accbuf[q];
            const float norm  = sqrtf((nsh[0] + nsh[1]) + (nsh[2] + nsh[3]));
            const float inv   = 1.0f / ((norm + kEPS) * (16.0f + kEPS));
            sims[(size_t)q * kNDB + n] = total * inv;
        }
    }
}

// ---------------------------------------------------------------------------
// Phase 2: per-query argmax over 8192 (first-max tie-break = lowest index),
// predictions = float(db_classes[argmax]), unit_sim = max.
// ---------------------------------------------------------------------------
__global__ void argmax_kernel(const float* __restrict__ sims,
                              const int* __restrict__ db_classes,
                              float* __restrict__ preds,
                              float* __restrict__ unit) {
    const int q = blockIdx.x;
    const int t = threadIdx.x;
    const float* row = sims + (size_t)q * kNDB;

    float best = -1e30f;
    int bidx = kNDB;
    for (int n = t; n < kNDB; n += 256) {   // increasing n: '>' keeps first max
        const float v = row[n];
        if (v > best) { best = v; bidx = n; }
    }

    __shared__ float bv[256];
    __shared__ int   bi[256];
    bv[t] = best;
    bi[t] = bidx;
    __syncthreads();
    for (int s2 = 128; s2 > 0; s2 >>= 1) {
        if (t < s2) {
            const float ov = bv[t + s2];
            const int   oi = bi[t + s2];
            if (ov > bv[t] || (ov == bv[t] && oi < bi[t])) {
                bv[t] = ov;
                bi[t] = oi;
            }
        }
        __syncthreads();
    }
    if (t == 0) {
        preds[q] = (float)db_classes[bi[0]];
        unit[q]  = bv[0];
    }
}

// ---------------------------------------------------------------------------
extern "C" void kernel_launch(void* const* d_in, const int* in_sizes, int n_in,
                              void* d_out, int out_size, void* d_ws, size_t ws_size,
                              hipStream_t stream) {
    const int*   seq        = (const int*)d_in[0];     // (8, 1024) int32
    const int*   kp         = (const int*)d_in[1];     // (8, 17)   int32
    const float* db         = (const float*)d_in[2];   // (8192, 128, 256) f32
    const int*   db_classes = (const int*)d_in[3];     // (8192,)   int32

    float* out   = (float*)d_out;                 // sims | preds | unit_sim
    float* preds = out + (size_t)kNQ * kNDB;      // + 1048576
    float* unit  = preds + kNQ;                   // + 128

    uint16_t* bkt  = (uint16_t*)d_ws;             // 256 KiB bucket table
    uint16_t* cnts = (uint16_t*)((char*)d_ws + 256 * 1024);   // 2 KiB counts

    build_addr_kernel<<<kNQ, kL2, 0, stream>>>(seq, kp, bkt, cnts);
    sim_kernel<<<kNDB, 512, 0, stream>>>(db, bkt, cnts, out);
    argmax_kernel<<<kNQ, 256, 0, stream>>>(out, db_classes, preds, unit);
}

// Round 8
// 233.418 us; speedup vs baseline: 1.2644x; 1.2644x over previous
//
#include <hip/hip_runtime.h>
#include <stdint.h>

// Problem constants (from reference):
constexpr int kB   = 8;
constexpr int kL1  = 1024;
constexpr int kC   = 128;
constexpr int kL2  = 256;
constexpr int kS   = 16;
constexpr int kNQ  = kB * kS;        // 128 queries
constexpr int kNDB = 8192;
constexpr float kEPS = 1e-8f;
constexpr int kRow = kC * kL2;       // 32768 floats per database row

constexpr int kTL2  = 64;            // l2 per LDS chunk (4 chunks per row)
constexpr int kPAD  = 129;           // LDS tile pitch (l2-major, padded)
constexpr int kGrid = 512;           // persistent blocks (2 per CU)
constexpr int kGens = kNDB / kGrid;  // 16 rows per block

// Raw barrier: LDS visibility via lgkmcnt(0), NO vmcnt drain -- global loads
// stay in flight across it (T4 pattern, proven rounds 4-5).
#define BARRIER_LG()                                          \
    do {                                                      \
        asm volatile("s_waitcnt lgkmcnt(0)" ::: "memory");    \
        __builtin_amdgcn_s_barrier();                         \
        asm volatile("" ::: "memory");                        \
    } while (0)

// ---------------------------------------------------------------------------
// Phase 0: gather-address table (round-5 version, proven). Stores BYTE
// offsets ((l2&63)*129 + c)*4 <= 33016, fits uint16.
// pos = f32(start) + f32(end-start)*((l2+0.5)/256) -- mul then add, NO fma,
// matching jnp's separately-rounded ops.
// ---------------------------------------------------------------------------
__global__ void build_addr_kernel(const int* __restrict__ seq,
                                  const int* __restrict__ kp,
                                  uint16_t* __restrict__ addr16) {
    const int q  = blockIdx.x;    // 0..127
    const int l2 = threadIdx.x;   // 0..255
    const int b = q >> 4;
    const int s = q & 15;
    int start = kp[b * (kS + 1) + s];
    int end_  = kp[b * (kS + 1) + s + 1];
    if (end_ < start + 1) end_ = start + 1;
    const float frac = (l2 + 0.5f) * (1.0f / 256.0f);   // exact (pow2 divide)
    const float pos = __fadd_rn((float)start, __fmul_rn((float)(end_ - start), frac));
    int idx = (int)pos;                                  // trunc, pos >= 0
    idx = idx < 0 ? 0 : (idx > kL1 - 1 ? kL1 - 1 : idx);
    const int c = seq[b * kL1 + idx];
    addr16[q * kL2 + l2] = (uint16_t)((((l2 & (kTL2 - 1)) * kPAD) + c) * 4);
}

// ---------------------------------------------------------------------------
// Producer helpers (round-5 geometry, proven):
//   j = (t + 256k)*4 flat float index in a 128c x 64l2 chunk
//   c = j>>6, l2l = j&63 -> 16-lane groups read 256 B contiguous (coalesced).
// LDS tile transposed+padded tile[l2l*129 + c]: ds_write banks (l2l+c)&31
// -> 2 lanes/bank (free); gather reads spread by random c.
// ---------------------------------------------------------------------------
__device__ __forceinline__ void stage_load(const float* __restrict__ rowp,
                                           int chunk, float4 (&buf)[8], int t) {
    #pragma unroll
    for (int k = 0; k < 8; ++k) {
        const int j   = (t + 256 * k) * 4;
        const int c   = j >> 6;
        const int l2l = j & 63;
        buf[k] = *reinterpret_cast<const float4*>(
            rowp + c * kL2 + chunk * kTL2 + l2l);
    }
}

__device__ __forceinline__ void stage_write(float* tile, const float4 (&buf)[8],
                                            int t, float& nrm) {
    #pragma unroll
    for (int k = 0; k < 8; ++k) {
        const int j   = (t + 256 * k) * 4;
        const int c   = j >> 6;
        const int l2l = j & 63;
        const float4 v = buf[k];
        nrm = fmaf(v.x, v.x, nrm);
        nrm = fmaf(v.y, v.y, nrm);
        nrm = fmaf(v.z, v.z, nrm);
        nrm = fmaf(v.w, v.w, nrm);
        tile[(l2l + 0) * kPAD + c] = v.x;
        tile[(l2l + 1) * kPAD + c] = v.y;
        tile[(l2l + 2) * kPAD + c] = v.z;
        tile[(l2l + 3) * kPAD + c] = v.w;
    }
}

// Consumer helper: 32 gathers from precomputed BYTE offsets (uniform cost).
__device__ __forceinline__ void gather32(const float* tile,
                                         const uint16_t* __restrict__ ap,
                                         float& a0, float& a1, float& a2, float& a3) {
    const char* tb = (const char*)tile;
    #pragma unroll
    for (int g = 0; g < 4; ++g) {
        union { uint4 v; uint16_t u[8]; } pk;
        pk.v = *reinterpret_cast<const uint4*>(ap + g * 8);
        a0 += *(const float*)(tb + pk.u[0]);
        a1 += *(const float*)(tb + pk.u[1]);
        a2 += *(const float*)(tb + pk.u[2]);
        a3 += *(const float*)(tb + pk.u[3]);
        a0 += *(const float*)(tb + pk.u[4]);
        a1 += *(const float*)(tb + pk.u[5]);
        a2 += *(const float*)(tb + pk.u[6]);
        a3 += *(const float*)(tb + pk.u[7]);
    }
}

// ---------------------------------------------------------------------------
// Phase 1: PERSISTENT blocks. 512 blocks x 512 threads; block b owns rows
// n = j*512 + b, j=0..15. Waves 0-3: producers stream the continuous chunk
// stream (64 chunks) through reg double-buffers into ping-pong LDS tiles --
// load issue NEVER stops across row boundaries (row j+1 ch0/ch1 issued while
// writing row j ch2/ch3). Waves 4-7: consumers gather one phase behind.
// Window p (between BAR_p and BAR_{p+1}): producer writes tile[p&1], consumer
// reads tile[(p-1)&1] -- always disjoint. Per-row handoff is parity-double-
// buffered: nsh[j&1] published window 4j+3; accbuf[j&1] written window 4j+4;
// sims row j written window 4j+5. 65 lgkm-only barriers on both wave paths.
// LDS 67.1 KB -> 2 blocks/CU.
// ---------------------------------------------------------------------------
__launch_bounds__(512, 2)
__global__ void sim_kernel(const float* __restrict__ db,
                           const uint16_t* __restrict__ addr16,
                           float* __restrict__ sims) {
    __shared__ float tileA[kTL2 * kPAD];   // 33,024 B
    __shared__ float tileB[kTL2 * kPAD];   // 33,024 B
    __shared__ float accbuf[2][128];
    __shared__ float nsh[2][4];

    const int blk = blockIdx.x;
    const int t = threadIdx.x;

    if (t < 256) {
        // ================= PRODUCER =================
        float4 bufA[8], bufB[8];
        const float* rp = db + (size_t)blk * kRow;
        stage_load(rp, 0, bufA, t);
        stage_load(rp, 1, bufB, t);
        float nrm = 0.f;

        #pragma unroll 1
        for (int j = 0; j < kGens; ++j) {
            const float* rpn = rp + (size_t)kGrid * kRow;   // next row

            // window 4j: write ch0 (bufA); issue ch2 -> bufA
            stage_write(tileA, bufA, t, nrm);
            stage_load(rp, 2, bufA, t);
            BARRIER_LG();

            // window 4j+1: write ch1 (bufB); issue ch3 -> bufB
            stage_write(tileB, bufB, t, nrm);
            stage_load(rp, 3, bufB, t);
            BARRIER_LG();

            // window 4j+2: write ch2 (bufA); issue next-row ch0 -> bufA
            stage_write(tileA, bufA, t, nrm);
            if (j < kGens - 1) stage_load(rpn, 0, bufA, t);
            BARRIER_LG();

            // window 4j+3: write ch3 (bufB); issue next-row ch1 -> bufB;
            // publish this row's norm (parity slot), reset.
            stage_write(tileB, bufB, t, nrm);
            if (j < kGens - 1) stage_load(rpn, 1, bufB, t);
            float nw = nrm;
            #pragma unroll
            for (int off = 32; off > 0; off >>= 1) nw += __shfl_down(nw, off);
            if ((t & 63) == 0) nsh[j & 1][t >> 6] = nw;
            nrm = 0.f;
            BARRIER_LG();

            rp = rpn;
        }
        BARRIER_LG();                      // final handoff window
    } else {
        // ================= CONSUMER =================
        const int u = t - 256;
        const int q = u & 127;
        const int h = u >> 7;              // wave-uniform (waves 4,5 vs 6,7)
        const uint16_t* aq = addr16 + q * kL2 + h * 32;
        float* simq = sims + (size_t)q * kNDB + blk;

        float a0 = 0.f, a1 = 0.f, a2 = 0.f, a3 = 0.f;
        float prev_part = 0.f;

        #pragma unroll 1
        for (int j = 0; j < kGens; ++j) {
            BARRIER_LG();                  // enter window 4j+1
            if (h == 0 && j > 0) {         // finish row j-1
                const int pj = j - 1;
                const float total = prev_part + accbuf[pj & 1][q];
                const float norm  = sqrtf((nsh[pj & 1][0] + nsh[pj & 1][1]) +
                                          (nsh[pj & 1][2] + nsh[pj & 1][3]));
                const float inv   = 1.0f / ((norm + kEPS) * (16.0f + kEPS));
                simq[(size_t)pj * kGrid] = total * inv;
            }
            gather32(tileA, aq + 0 * kTL2, a0, a1, a2, a3);   // ch0
            BARRIER_LG();                  // window 4j+2
            gather32(tileB, aq + 1 * kTL2, a0, a1, a2, a3);   // ch1
            BARRIER_LG();                  // window 4j+3
            gather32(tileA, aq + 2 * kTL2, a0, a1, a2, a3);   // ch2
            BARRIER_LG();                  // window 4j+4
            gather32(tileB, aq + 3 * kTL2, a0, a1, a2, a3);   // ch3
            const float part = (a0 + a1) + (a2 + a3);
            if (h) accbuf[j & 1][q] = part;
            prev_part = part;
            a0 = a1 = a2 = a3 = 0.f;
        }
        BARRIER_LG();                      // final handoff window
        if (h == 0) {                      // finish row 15
            const int pj = kGens - 1;
            const float total = prev_part + accbuf[pj & 1][q];
            const float norm  = sqrtf((nsh[pj & 1][0] + nsh[pj & 1][1]) +
                                      (nsh[pj & 1][2] + nsh[pj & 1][3]));
            const float inv   = 1.0f / ((norm + kEPS) * (16.0f + kEPS));
            simq[(size_t)pj * kGrid] = total * inv;
        }
    }
}

// ---------------------------------------------------------------------------
// Phase 2: per-query argmax over 8192 (first-max tie-break = lowest index),
// predictions = float(db_classes[argmax]), unit_sim = max.
// ---------------------------------------------------------------------------
__global__ void argmax_kernel(const float* __restrict__ sims,
                              const int* __restrict__ db_classes,
                              float* __restrict__ preds,
                              float* __restrict__ unit) {
    const int q = blockIdx.x;
    const int t = threadIdx.x;
    const float* row = sims + (size_t)q * kNDB;

    float best = -1e30f;
    int bidx = kNDB;
    for (int n = t; n < kNDB; n += 256) {   // increasing n: '>' keeps first max
        const float v = row[n];
        if (v > best) { best = v; bidx = n; }
    }

    __shared__ float bv[256];
    __shared__ int   bi[256];
    bv[t] = best;
    bi[t] = bidx;
    __syncthreads();
    for (int s2 = 128; s2 > 0; s2 >>= 1) {
        if (t < s2) {
            const float ov = bv[t + s2];
            const int   oi = bi[t + s2];
            if (ov > bv[t] || (ov == bv[t] && oi < bi[t])) {
                bv[t] = ov;
                bi[t] = oi;
            }
        }
        __syncthreads();
    }
    if (t == 0) {
        preds[q] = (float)db_classes[bi[0]];
        unit[q]  = bv[0];
    }
}

// ---------------------------------------------------------------------------
extern "C" void kernel_launch(void* const* d_in, const int* in_sizes, int n_in,
                              void* d_out, int out_size, void* d_ws, size_t ws_size,
                              hipStream_t stream) {
    const int*   seq        = (const int*)d_in[0];     // (8, 1024) int32
    const int*   kp         = (const int*)d_in[1];     // (8, 17)   int32
    const float* db         = (const float*)d_in[2];   // (8192, 128, 256) f32
    const int*   db_classes = (const int*)d_in[3];     // (8192,)   int32

    float* out   = (float*)d_out;                 // sims | preds | unit_sim
    float* preds = out + (size_t)kNQ * kNDB;      // + 1048576
    float* unit  = preds + kNQ;                   // + 128

    uint16_t* addr16 = (uint16_t*)d_ws;           // 64 KiB scratch

    build_addr_kernel<<<kNQ, kL2, 0, stream>>>(seq, kp, addr16);
    sim_kernel<<<kGrid, 512, 0, stream>>>(db, addr16, out);
    argmax_kernel<<<kNQ, 256, 0, stream>>>(out, db_classes, preds, unit);
}

// Round 9
// 230.631 us; speedup vs baseline: 1.2796x; 1.0121x over previous
//
#include <hip/hip_runtime.h>
#include <stdint.h>

// Problem constants (from reference):
constexpr int kB   = 8;
constexpr int kL1  = 1024;
constexpr int kC   = 128;
constexpr int kL2  = 256;
constexpr int kS   = 16;
constexpr int kNQ  = kB * kS;        // 128 queries
constexpr int kNDB = 8192;
constexpr float kEPS = 1e-8f;
constexpr int kRow = kC * kL2;       // 32768 floats per database row

constexpr int kTL2  = 64;            // l2 per LDS chunk (4 chunks per row)
constexpr int kPAD  = 129;           // LDS tile pitch (l2-major, padded)
constexpr int kGrid = 512;           // persistent blocks (2 per CU)
constexpr int kGens = kNDB / kGrid;  // 16 CONSECUTIVE rows per block

// Raw barrier: LDS visibility via lgkmcnt(0), NO vmcnt drain -- global loads
// stay in flight across it (T4 pattern, proven rounds 4-8).
#define BARRIER_LG()                                          \
    do {                                                      \
        asm volatile("s_waitcnt lgkmcnt(0)" ::: "memory");    \
        __builtin_amdgcn_s_barrier();                         \
        asm volatile("" ::: "memory");                        \
    } while (0)

// ---------------------------------------------------------------------------
// Phase 0: gather-address table (proven). Stores BYTE offsets
// ((l2&63)*129 + c)*4 <= 33016, fits uint16.
// pos = f32(start) + f32(end-start)*((l2+0.5)/256) -- mul then add, NO fma,
// matching jnp's separately-rounded ops.
// ---------------------------------------------------------------------------
__global__ void build_addr_kernel(const int* __restrict__ seq,
                                  const int* __restrict__ kp,
                                  uint16_t* __restrict__ addr16) {
    const int q  = blockIdx.x;    // 0..127
    const int l2 = threadIdx.x;   // 0..255
    const int b = q >> 4;
    const int s = q & 15;
    int start = kp[b * (kS + 1) + s];
    int end_  = kp[b * (kS + 1) + s + 1];
    if (end_ < start + 1) end_ = start + 1;
    const float frac = (l2 + 0.5f) * (1.0f / 256.0f);   // exact (pow2 divide)
    const float pos = __fadd_rn((float)start, __fmul_rn((float)(end_ - start), frac));
    int idx = (int)pos;                                  // trunc, pos >= 0
    idx = idx < 0 ? 0 : (idx > kL1 - 1 ? kL1 - 1 : idx);
    const int c = seq[b * kL1 + idx];
    addr16[q * kL2 + l2] = (uint16_t)((((l2 & (kTL2 - 1)) * kPAD) + c) * 4);
}

// ---------------------------------------------------------------------------
// Producer helpers (proven geometry):
//   j = (t + 256k)*4 flat float index in a 128c x 64l2 chunk
//   c = j>>6, l2l = j&63 -> 16-lane groups read 256 B contiguous (coalesced).
// LDS tile transposed+padded tile[l2l*129 + c]: ds_write banks (l2l+c)&31
// -> 2 lanes/bank (free); gather reads spread by random c.
// ---------------------------------------------------------------------------
__device__ __forceinline__ void stage_load(const float* __restrict__ rowp,
                                           int chunk, float4 (&buf)[8], int t) {
    #pragma unroll
    for (int k = 0; k < 8; ++k) {
        const int j   = (t + 256 * k) * 4;
        const int c   = j >> 6;
        const int l2l = j & 63;
        buf[k] = *reinterpret_cast<const float4*>(
            rowp + c * kL2 + chunk * kTL2 + l2l);
    }
}

__device__ __forceinline__ void stage_write(float* tile, const float4 (&buf)[8],
                                            int t, float& nrm) {
    #pragma unroll
    for (int k = 0; k < 8; ++k) {
        const int j   = (t + 256 * k) * 4;
        const int c   = j >> 6;
        const int l2l = j & 63;
        const float4 v = buf[k];
        nrm = fmaf(v.x, v.x, nrm);
        nrm = fmaf(v.y, v.y, nrm);
        nrm = fmaf(v.z, v.z, nrm);
        nrm = fmaf(v.w, v.w, nrm);
        tile[(l2l + 0) * kPAD + c] = v.x;
        tile[(l2l + 1) * kPAD + c] = v.y;
        tile[(l2l + 2) * kPAD + c] = v.z;
        tile[(l2l + 3) * kPAD + c] = v.w;
    }
}

// Consumer helper: 32 gathers from precomputed BYTE offsets (uniform cost).
__device__ __forceinline__ void gather32(const float* tile,
                                         const uint16_t* __restrict__ ap,
                                         float& a0, float& a1, float& a2, float& a3) {
    const char* tb = (const char*)tile;
    #pragma unroll
    for (int g = 0; g < 4; ++g) {
        union { uint4 v; uint16_t u[8]; } pk;
        pk.v = *reinterpret_cast<const uint4*>(ap + g * 8);
        a0 += *(const float*)(tb + pk.u[0]);
        a1 += *(const float*)(tb + pk.u[1]);
        a2 += *(const float*)(tb + pk.u[2]);
        a3 += *(const float*)(tb + pk.u[3]);
        a0 += *(const float*)(tb + pk.u[4]);
        a1 += *(const float*)(tb + pk.u[5]);
        a2 += *(const float*)(tb + pk.u[6]);
        a3 += *(const float*)(tb + pk.u[7]);
    }
}

// ---------------------------------------------------------------------------
// Phase 1: PERSISTENT blocks, CONSECUTIVE row ownership. 512 blocks x 512
// threads; block b owns rows n = b*16 + j, j=0..15 -> each block reads a
// contiguous 2 MiB db span, and all 16 partial writes to each 64-B sims line
// (q, b*16..b*16+15) come from THIS block: the line is fetched into this
// XCD's L2 once, absorbs 16 writes, written back once (kills the 16-way
// cross-XCD RMW amplification of rounds 5/8).
// Waves 0-3: producers; waves 4-7: consumers (identical schedule to r8).
// Window p: producer writes tile[p&1], consumer reads tile[(p-1)&1].
// Per-row handoff parity-double-buffered (nsh/accbuf). 65 lgkm barriers.
// LDS 67.1 KB -> 2 blocks/CU.
// ---------------------------------------------------------------------------
__launch_bounds__(512, 2)
__global__ void sim_kernel(const float* __restrict__ db,
                           const uint16_t* __restrict__ addr16,
                           float* __restrict__ sims) {
    __shared__ float tileA[kTL2 * kPAD];   // 33,024 B
    __shared__ float tileB[kTL2 * kPAD];   // 33,024 B
    __shared__ float accbuf[2][128];
    __shared__ float nsh[2][4];

    const int blk  = blockIdx.x;
    const int row0 = blk * kGens;          // first owned row
    const int t = threadIdx.x;

    if (t < 256) {
        // ================= PRODUCER =================
        float4 bufA[8], bufB[8];
        const float* rp = db + (size_t)row0 * kRow;
        stage_load(rp, 0, bufA, t);
        stage_load(rp, 1, bufB, t);
        float nrm = 0.f;

        #pragma unroll 1
        for (int j = 0; j < kGens; ++j) {
            const float* rpn = rp + kRow;            // next (consecutive) row

            // window 4j: write ch0 (bufA); issue ch2 -> bufA
            stage_write(tileA, bufA, t, nrm);
            stage_load(rp, 2, bufA, t);
            BARRIER_LG();

            // window 4j+1: write ch1 (bufB); issue ch3 -> bufB
            stage_write(tileB, bufB, t, nrm);
            stage_load(rp, 3, bufB, t);
            BARRIER_LG();

            // window 4j+2: write ch2 (bufA); issue next-row ch0 -> bufA
            stage_write(tileA, bufA, t, nrm);
            if (j < kGens - 1) stage_load(rpn, 0, bufA, t);
            BARRIER_LG();

            // window 4j+3: write ch3 (bufB); issue next-row ch1 -> bufB;
            // publish this row's norm (parity slot), reset.
            stage_write(tileB, bufB, t, nrm);
            if (j < kGens - 1) stage_load(rpn, 1, bufB, t);
            float nw = nrm;
            #pragma unroll
            for (int off = 32; off > 0; off >>= 1) nw += __shfl_down(nw, off);
            if ((t & 63) == 0) nsh[j & 1][t >> 6] = nw;
            nrm = 0.f;
            BARRIER_LG();

            rp = rpn;
        }
        BARRIER_LG();                      // final handoff window
    } else {
        // ================= CONSUMER =================
        const int u = t - 256;
        const int q = u & 127;
        const int h = u >> 7;              // wave-uniform (waves 4,5 vs 6,7)
        const uint16_t* aq = addr16 + q * kL2 + h * 32;
        float* simq = sims + (size_t)q * kNDB + row0;   // contiguous 16 floats

        float a0 = 0.f, a1 = 0.f, a2 = 0.f, a3 = 0.f;
        float prev_part = 0.f;

        #pragma unroll 1
        for (int j = 0; j < kGens; ++j) {
            BARRIER_LG();                  // enter window 4j+1
            if (h == 0 && j > 0) {         // finish row j-1
                const int pj = j - 1;
                const float total = prev_part + accbuf[pj & 1][q];
                const float norm  = sqrtf((nsh[pj & 1][0] + nsh[pj & 1][1]) +
                                          (nsh[pj & 1][2] + nsh[pj & 1][3]));
                const float inv   = 1.0f / ((norm + kEPS) * (16.0f + kEPS));
                simq[pj] = total * inv;    // same 64-B line all 16 gens
            }
            gather32(tileA, aq + 0 * kTL2, a0, a1, a2, a3);   // ch0
            BARRIER_LG();                  // window 4j+2
            gather32(tileB, aq + 1 * kTL2, a0, a1, a2, a3);   // ch1
            BARRIER_LG();                  // window 4j+3
            gather32(tileA, aq + 2 * kTL2, a0, a1, a2, a3);   // ch2
            BARRIER_LG();                  // window 4j+4
            gather32(tileB, aq + 3 * kTL2, a0, a1, a2, a3);   // ch3
            const float part = (a0 + a1) + (a2 + a3);
            if (h) accbuf[j & 1][q] = part;
            prev_part = part;
            a0 = a1 = a2 = a3 = 0.f;
        }
        BARRIER_LG();                      // final handoff window
        if (h == 0) {                      // finish row 15
            const int pj = kGens - 1;
            const float total = prev_part + accbuf[pj & 1][q];
            const float norm  = sqrtf((nsh[pj & 1][0] + nsh[pj & 1][1]) +
                                      (nsh[pj & 1][2] + nsh[pj & 1][3]));
            const float inv   = 1.0f / ((norm + kEPS) * (16.0f + kEPS));
            simq[pj] = total * inv;
        }
    }
}

// ---------------------------------------------------------------------------
// Phase 2: per-query argmax over 8192 (first-max tie-break = lowest index),
// predictions = float(db_classes[argmax]), unit_sim = max.
// ---------------------------------------------------------------------------
__global__ void argmax_kernel(const float* __restrict__ sims,
                              const int* __restrict__ db_classes,
                              float* __restrict__ preds,
                              float* __restrict__ unit) {
    const int q = blockIdx.x;
    const int t = threadIdx.x;
    const float* row = sims + (size_t)q * kNDB;

    float best = -1e30f;
    int bidx = kNDB;
    for (int n = t; n < kNDB; n += 256) {   // increasing n: '>' keeps first max
        const float v = row[n];
        if (v > best) { best = v; bidx = n; }
    }

    __shared__ float bv[256];
    __shared__ int   bi[256];
    bv[t] = best;
    bi[t] = bidx;
    __syncthreads();
    for (int s2 = 128; s2 > 0; s2 >>= 1) {
        if (t < s2) {
            const float ov = bv[t + s2];
            const int   oi = bi[t + s2];
            if (ov > bv[t] || (ov == bv[t] && oi < bi[t])) {
                bv[t] = ov;
                bi[t] = oi;
            }
        }
        __syncthreads();
    }
    if (t == 0) {
        preds[q] = (float)db_classes[bi[0]];
        unit[q]  = bv[0];
    }
}

// ---------------------------------------------------------------------------
extern "C" void kernel_launch(void* const* d_in, const int* in_sizes, int n_in,
                              void* d_out, int out_size, void* d_ws, size_t ws_size,
                              hipStream_t stream) {
    const int*   seq        = (const int*)d_in[0];     // (8, 1024) int32
    const int*   kp         = (const int*)d_in[1];     // (8, 17)   int32
    const float* db         = (const float*)d_in[2];   // (8192, 128, 256) f32
    const int*   db_classes = (const int*)d_in[3];     // (8192,)   int32

    float* out   = (float*)d_out;                 // sims | preds | unit_sim
    float* preds = out + (size_t)kNQ * kNDB;      // + 1048576
    float* unit  = preds + kNQ;                   // + 128

    uint16_t* addr16 = (uint16_t*)d_ws;           // 64 KiB scratch

    build_addr_kernel<<<kNQ, kL2, 0, stream>>>(seq, kp, addr16);
    sim_kernel<<<kGrid, 512, 0, stream>>>(db, addr16, out);
    argmax_kernel<<<kNQ, 256, 0, stream>>>(out, db_classes, preds, unit);
}

// Round 10
// 222.817 us; speedup vs baseline: 1.3245x; 1.0351x over previous
//
#include <hip/hip_runtime.h>
#include <stdint.h>

// Problem constants (from reference):
constexpr int kB   = 8;
constexpr int kL1  = 1024;
constexpr int kC   = 128;
constexpr int kL2  = 256;
constexpr int kS   = 16;
constexpr int kNQ  = kB * kS;        // 128 queries
constexpr int kNDB = 8192;
constexpr float kEPS = 1e-8f;
constexpr int kRow = kC * kL2;       // 32768 floats per database row

constexpr int kGrid = 256;           // persistent blocks, 1 per CU
constexpr int kGens = kNDB / kGrid;  // 32 CONSECUTIVE rows per block

// Raw barrier: LDS visibility via lgkmcnt(0), NO vmcnt drain -- global loads
// stay in flight across it (proven rounds 4-9).
#define BARRIER_LG()                                          \
    do {                                                      \
        asm volatile("s_waitcnt lgkmcnt(0)" ::: "memory");    \
        __builtin_amdgcn_s_barrier();                         \
        asm volatile("" ::: "memory");                        \
    } while (0)

// ---------------------------------------------------------------------------
// Phase 0: per-consumer-thread gather address table, rotation baked in.
// Consumer thread (q, h) gather g reads LDS element c(q,l2)*256 + l2 with
//   l2 = h*64 + ((q&63) + g) & 63         (lane rotation)
// Bank of that element = l2 & 31 = (lane+g)&31 -> per wave instr each bank
// serves exactly 2 lanes (free) REGARDLESS of c. Table stores BYTE offsets
// (u32), laid out [q][h][g] so each consumer's 64 entries are contiguous.
// pos = f32(start) + f32(end-start)*((l2+0.5)/256) -- mul then add, NO fma.
// ---------------------------------------------------------------------------
__global__ void build_table_kernel(const int* __restrict__ seq,
                                   const int* __restrict__ kp,
                                   uint32_t* __restrict__ table) {
    __shared__ int csh[kL2];
    const int q = blockIdx.x;     // 0..127
    const int s0 = threadIdx.x;   // 0..255
    const int b = q >> 4;
    const int s = q & 15;
    int start = kp[b * (kS + 1) + s];
    int end_  = kp[b * (kS + 1) + s + 1];
    if (end_ < start + 1) end_ = start + 1;
    {
        const int l2 = s0;
        const float frac = (l2 + 0.5f) * (1.0f / 256.0f);   // exact
        const float pos = __fadd_rn((float)start,
                                    __fmul_rn((float)(end_ - start), frac));
        int idx = (int)pos;                                  // trunc, pos >= 0
        idx = idx < 0 ? 0 : (idx > kL1 - 1 ? kL1 - 1 : idx);
        csh[l2] = seq[b * kL1 + idx];
    }
    __syncthreads();
    const int h = s0 >> 6;
    const int g = s0 & 63;
    const int l2r = h * 64 + (((q & 63) + g) & 63);
    const int c = csh[l2r];
    table[(q * 4 + h) * 64 + g] = (uint32_t)((c * kL2 + l2r) * 4);
}

// ---------------------------------------------------------------------------
// Phase 1: PERSISTENT 1024-thread blocks, 1 per CU, 32 consecutive rows each
// -> each block's db reads are ONE strictly sequential 4 MiB stream (the
// point of this round: kill the 256B/1KiB interleaved pattern of r5-r9).
//
// Waves 0-7 (t<512): PRODUCERS. Full row in regs (16 float4/thread).
//   W_j: ds_write_b128 row j to tile (counted vmcnt per reg), fuse norm fma,
//        publish nshp[j&1]. G_j: issue row j+1's 16 loads (fly across
//        barriers + whole next W via counted vmcnt).
// Waves 8-15: CONSUMERS. One addr-reg preload (64 u32, static idx), then per
//   row: W_j finalize row j-1 (accp/nshp parity buffers) -> sims;
//   G_j 64 conflict-free rotated gathers + partial to accp.
// 2 lgkm-only barriers per row. LDS: 128 KiB tile + 3.1 KiB handoff.
// ---------------------------------------------------------------------------
__launch_bounds__(1024, 1)
__global__ void sim_kernel(const float* __restrict__ db,
                           const uint32_t* __restrict__ table,
                           float* __restrict__ sims) {
    __shared__ float tile[kRow];          // 131,072 B, natural [c][l2]
    __shared__ float accp[2][3][128];     // consumer partials h=1..3, parity
    __shared__ float nshp[2][8];          // producer wave norm partials

    const int blk  = blockIdx.x;
    const int row0 = blk * kGens;
    const int t = threadIdx.x;

    if (t < 512) {
        // ================= PRODUCER =================
        const int p = t;
        const float* rp = db + (size_t)row0 * kRow;
        float4 buf[16];
        #pragma unroll
        for (int k = 0; k < 16; ++k)
            buf[k] = *reinterpret_cast<const float4*>(rp + (p + 512 * k) * 4);

        #pragma unroll 1
        for (int j = 0; j < kGens; ++j) {
            // ---- W_j: write row j + fused norm ----
            float nr = 0.f;
            #pragma unroll
            for (int k = 0; k < 16; ++k) {
                const float4 v = buf[k];   // counted vmcnt wait on this reg
                nr = fmaf(v.x, v.x, nr);
                nr = fmaf(v.y, v.y, nr);
                nr = fmaf(v.z, v.z, nr);
                nr = fmaf(v.w, v.w, nr);
                *reinterpret_cast<float4*>(&tile[(p + 512 * k) * 4]) = v;
            }
            #pragma unroll
            for (int off = 32; off > 0; off >>= 1) nr += __shfl_down(nr, off);
            if ((t & 63) == 0) nshp[j & 1][t >> 6] = nr;
            BARRIER_LG();                  // row j visible; consumers enter G_j

            // ---- G_j: issue row j+1 loads (land during next W) ----
            if (j < kGens - 1) {
                const float* rpn = rp + kRow;
                #pragma unroll
                for (int k = 0; k < 16; ++k)
                    buf[k] = *reinterpret_cast<const float4*>(
                        rpn + (p + 512 * k) * 4);
                rp = rpn;
            }
            BARRIER_LG();                  // consumers done gathering row j
        }
    } else {
        // ================= CONSUMER =================
        const int u = t - 512;
        const int q = u & 127;
        const int h = u >> 7;              // wave-uniform (2 waves per h)
        float* simq = sims + (size_t)q * kNDB + row0;

        // one-time addr preload: 64 byte-offsets, rotation baked in
        uint32_t adr[64];
        {
            const uint4* tp4 = reinterpret_cast<const uint4*>(
                table + (q * 4 + h) * 64);
            #pragma unroll
            for (int g4 = 0; g4 < 16; ++g4) {
                const uint4 v = tp4[g4];
                adr[g4 * 4 + 0] = v.x;
                adr[g4 * 4 + 1] = v.y;
                adr[g4 * 4 + 2] = v.z;
                adr[g4 * 4 + 3] = v.w;
            }
        }

        const char* tb = reinterpret_cast<const char*>(tile);
        float prev_part = 0.f;

        #pragma unroll 1
        for (int j = 0; j < kGens; ++j) {
            // ---- W_j window: finalize row j-1 ----
            if (h == 0 && j > 0) {
                const int pj = (j - 1) & 1;
                const float total = prev_part + accp[pj][0][q] +
                                    accp[pj][1][q] + accp[pj][2][q];
                const float n2 =
                    ((nshp[pj][0] + nshp[pj][1]) + (nshp[pj][2] + nshp[pj][3])) +
                    ((nshp[pj][4] + nshp[pj][5]) + (nshp[pj][6] + nshp[pj][7]));
                const float inv = 1.0f / ((sqrtf(n2) + kEPS) * (16.0f + kEPS));
                simq[j - 1] = total * inv;
            }
            BARRIER_LG();                  // row j staged

            // ---- G_j: 64 rotated conflict-free gathers ----
            float a[8];
            #pragma unroll
            for (int i = 0; i < 8; ++i) a[i] = 0.f;
            #pragma unroll
            for (int g = 0; g < 64; ++g)
                a[g & 7] += *reinterpret_cast<const float*>(tb + adr[g]);
            const float part = ((a[0] + a[1]) + (a[2] + a[3])) +
                               ((a[4] + a[5]) + (a[6] + a[7]));
            if (h) accp[j & 1][h - 1][q] = part;
            prev_part = part;
            BARRIER_LG();                  // release tile for W_{j+1}
        }
        // finalize last row (accp/nshp published before final barrier)
        if (h == 0) {
            const int pj = (kGens - 1) & 1;
            const float total = prev_part + accp[pj][0][q] +
                                accp[pj][1][q] + accp[pj][2][q];
            const float n2 =
                ((nshp[pj][0] + nshp[pj][1]) + (nshp[pj][2] + nshp[pj][3])) +
                ((nshp[pj][4] + nshp[pj][5]) + (nshp[pj][6] + nshp[pj][7]));
            const float inv = 1.0f / ((sqrtf(n2) + kEPS) * (16.0f + kEPS));
            simq[kGens - 1] = total * inv;
        }
    }
}

// ---------------------------------------------------------------------------
// Phase 2: per-query argmax over 8192 (first-max tie-break = lowest index),
// predictions = float(db_classes[argmax]), unit_sim = max.
// ---------------------------------------------------------------------------
__global__ void argmax_kernel(const float* __restrict__ sims,
                              const int* __restrict__ db_classes,
                              float* __restrict__ preds,
                              float* __restrict__ unit) {
    const int q = blockIdx.x;
    const int t = threadIdx.x;
    const float* row = sims + (size_t)q * kNDB;

    float best = -1e30f;
    int bidx = kNDB;
    for (int n = t; n < kNDB; n += 256) {   // increasing n: '>' keeps first max
        const float v = row[n];
        if (v > best) { best = v; bidx = n; }
    }

    __shared__ float bv[256];
    __shared__ int   bi[256];
    bv[t] = best;
    bi[t] = bidx;
    __syncthreads();
    for (int s2 = 128; s2 > 0; s2 >>= 1) {
        if (t < s2) {
            const float ov = bv[t + s2];
            const int   oi = bi[t + s2];
            if (ov > bv[t] || (ov == bv[t] && oi < bi[t])) {
                bv[t] = ov;
                bi[t] = oi;
            }
        }
        __syncthreads();
    }
    if (t == 0) {
        preds[q] = (float)db_classes[bi[0]];
        unit[q]  = bv[0];
    }
}

// ---------------------------------------------------------------------------
extern "C" void kernel_launch(void* const* d_in, const int* in_sizes, int n_in,
                              void* d_out, int out_size, void* d_ws, size_t ws_size,
                              hipStream_t stream) {
    const int*   seq        = (const int*)d_in[0];     // (8, 1024) int32
    const int*   kp         = (const int*)d_in[1];     // (8, 17)   int32
    const float* db         = (const float*)d_in[2];   // (8192, 128, 256) f32
    const int*   db_classes = (const int*)d_in[3];     // (8192,)   int32

    float* out   = (float*)d_out;                 // sims | preds | unit_sim
    float* preds = out + (size_t)kNQ * kNDB;      // + 1048576
    float* unit  = preds + kNQ;                   // + 128

    uint32_t* table = (uint32_t*)d_ws;            // 128 KiB addr table

    build_table_kernel<<<kNQ, kL2, 0, stream>>>(seq, kp, table);
    sim_kernel<<<kGrid, 1024, 0, stream>>>(db, table, out);
    argmax_kernel<<<kNQ, 256, 0, stream>>>(out, db_classes, preds, unit);
}

// Round 11
// 222.521 us; speedup vs baseline: 1.3263x; 1.0013x over previous
//
#include <hip/hip_runtime.h>
#include <stdint.h>

// Problem constants (from reference):
constexpr int kB   = 8;
constexpr int kL1  = 1024;
constexpr int kC   = 128;
constexpr int kL2  = 256;
constexpr int kS   = 16;
constexpr int kNQ  = kB * kS;        // 128 queries
constexpr int kNDB = 8192;
constexpr float kEPS = 1e-8f;
constexpr int kRow = kC * kL2;       // 32768 floats per database row

constexpr int kGrid  = 256;          // persistent blocks, 1 per CU
constexpr int kGens  = kNDB / kGrid; // 32 CONSECUTIVE rows per block
constexpr int kHalfF = kRow / 2;     // 16384 floats per half tile (64 KiB)
constexpr int kNPh   = 2 * kGens;    // 64 half-row phases

// Raw barrier: LDS visibility via lgkmcnt(0), NO vmcnt drain -- global loads
// stay in flight across it (proven rounds 4-10).
#define BARRIER_LG()                                          \
    do {                                                      \
        asm volatile("s_waitcnt lgkmcnt(0)" ::: "memory");    \
        __builtin_amdgcn_s_barrier();                         \
        asm volatile("" ::: "memory");                        \
    } while (0)

// ---------------------------------------------------------------------------
// Phase 0: per-consumer gather address table, rotation baked in.
// Consumer (q,h), h=0..3, owns l2 = h*64 + ((q&63)+g)&63, g=0..63 -- h<2 in
// l2-half 0, h>=2 in half 1. Half-tile layout [c][l2&127] (128 f/row):
//   byte offset = (c*128 + (l2&127))*4 ; bank = ((q&63)+g)&31 -> 2 lanes/bank
//   per wave instr (FREE) regardless of the data-dependent c.
// pos = f32(start) + f32(end-start)*((l2+0.5)/256) -- mul then add, NO fma.
// ---------------------------------------------------------------------------
__global__ void build_table_kernel(const int* __restrict__ seq,
                                   const int* __restrict__ kp,
                                   uint32_t* __restrict__ table) {
    __shared__ int csh[kL2];
    const int q = blockIdx.x;     // 0..127
    const int s0 = threadIdx.x;   // 0..255
    const int b = q >> 4;
    const int s = q & 15;
    int start = kp[b * (kS + 1) + s];
    int end_  = kp[b * (kS + 1) + s + 1];
    if (end_ < start + 1) end_ = start + 1;
    {
        const int l2 = s0;
        const float frac = (l2 + 0.5f) * (1.0f / 256.0f);   // exact
        const float pos = __fadd_rn((float)start,
                                    __fmul_rn((float)(end_ - start), frac));
        int idx = (int)pos;                                  // trunc, pos >= 0
        idx = idx < 0 ? 0 : (idx > kL1 - 1 ? kL1 - 1 : idx);
        csh[l2] = seq[b * kL1 + idx];
    }
    __syncthreads();
    const int h = s0 >> 6;
    const int g = s0 & 63;
    const int l2r = h * 64 + (((q & 63) + g) & 63);
    const int c = csh[l2r];
    table[(q * 4 + h) * 64 + g] = (uint32_t)((c * 128 + (l2r & 127)) * 4);
}

// ---------------------------------------------------------------------------
// Producer helpers. Half hf of a row, float4 index f4 = p + 512k (k=0..7):
//   global = rowp + (f4>>5)*256 + hf*128 + (f4&31)*4   (2x512B runs per wave)
//   LDS    = tile_half[f4*4 .. +3]  (linear; banks 2 lanes/bank, free)
// ---------------------------------------------------------------------------
__device__ __forceinline__ void load_half(const float* __restrict__ rowp,
                                          int hf, float4 (&buf)[8], int p) {
    #pragma unroll
    for (int k = 0; k < 8; ++k) {
        const int f4 = p + 512 * k;
        buf[k] = *reinterpret_cast<const float4*>(
            rowp + (f4 >> 5) * kL2 + hf * 128 + (f4 & 31) * 4);
    }
}

__device__ __forceinline__ void write_half(float* tp, const float4 (&buf)[8],
                                           int p, float& nrm) {
    #pragma unroll
    for (int k = 0; k < 8; ++k) {
        const int f4 = p + 512 * k;
        const float4 v = buf[k];      // counted vmcnt wait on this reg only
        nrm = fmaf(v.x, v.x, nrm);
        nrm = fmaf(v.y, v.y, nrm);
        nrm = fmaf(v.z, v.z, nrm);
        nrm = fmaf(v.w, v.w, nrm);
        *reinterpret_cast<float4*>(tp + f4 * 4) = v;
    }
}

// ---------------------------------------------------------------------------
// Phase 1: PERSISTENT 1024-thread blocks, 1/CU, 32 consecutive rows. 64
// half-row phases; ping-pong 64 KiB tiles. Phase p: consumers gather half p
// from tile[p&1] WHILE producers ds_write half p+1 into tile[(p+1)&1] -- the
// counted-vmcnt stall on the staged regs IS the HBM pacing, now overlapped
// with the gathers instead of barrier-separated from them (the r10 bug).
// Loads for half p+2 issued mid-phase (full phase to land). 1 lgkm-only
// barrier per phase. Waves 0-7 producers; waves 8-15 consumers; per phase
// the matching-half consumer waves gather (4 waves), the off-half h==2
// waves finalize the previous row. LDS 132 KiB.
// ---------------------------------------------------------------------------
__launch_bounds__(1024, 1)
__global__ void sim_kernel(const float* __restrict__ db,
                           const uint32_t* __restrict__ table,
                           float* __restrict__ sims) {
    __shared__ float tile[2][kHalfF];     // 131,072 B
    __shared__ float accp[2][4][128];     // per-(row-parity, h, q) partials
    __shared__ float nshp[2][8];          // per-(row-parity, wave) norm parts

    const int blk  = blockIdx.x;
    const int row0 = blk * kGens;
    const int t = threadIdx.x;

    if (t < 512) {
        // ================= PRODUCER =================
        const int p = t;
        float4 buf[8];
        float nrm = 0.f;
        load_half(db + (size_t)row0 * kRow, 0, buf, p);
        write_half(tile[0], buf, p, nrm);            // prologue stage half 0
        load_half(db + (size_t)row0 * kRow, 1, buf, p);
        BARRIER_LG();                                // phase 0 begins

        #pragma unroll 1
        for (int ph = 0; ph < kNPh; ++ph) {
            // write half ph+1 -> tile[(ph+1)&1]; vmcnt pacing overlapped
            // with consumers' gathers of half ph from tile[ph&1]
            if (ph < kNPh - 1)
                write_half(tile[(ph + 1) & 1], buf, p, nrm);

            // even phase: half 2r+1 of row r=ph>>1 just written -> publish
            if ((ph & 1) == 0) {
                float nw = nrm;
                #pragma unroll
                for (int off = 32; off > 0; off >>= 1)
                    nw += __shfl_down(nw, off);
                if ((t & 63) == 0) nshp[(ph >> 1) & 1][t >> 6] = nw;
                nrm = 0.f;
            }

            // issue loads for half ph+2 (a full phase to land)
            if (ph + 2 < kNPh) {
                const int H = ph + 2;
                load_half(db + (size_t)(row0 + (H >> 1)) * kRow, H & 1, buf, p);
            }
            BARRIER_LG();
        }
    } else {
        // ================= CONSUMER =================
        const int u = t - 512;
        const int q = u & 127;
        const int h = u >> 7;              // 0..3, wave-uniform
        float* simq = sims + (size_t)q * kNDB + row0;

        uint32_t adr[64];                  // one-time addr preload (static idx)
        {
            const uint4* tp4 = reinterpret_cast<const uint4*>(
                table + (q * 4 + h) * 64);
            #pragma unroll
            for (int g4 = 0; g4 < 16; ++g4) {
                const uint4 v = tp4[g4];
                adr[g4 * 4 + 0] = v.x;
                adr[g4 * 4 + 1] = v.y;
                adr[g4 * 4 + 2] = v.z;
                adr[g4 * 4 + 3] = v.w;
            }
        }
        BARRIER_LG();                      // match producer prologue

        #pragma unroll 1
        for (int ph = 0; ph < kNPh; ++ph) {
            // off-half h==2 waves: finalize row (ph-2)/2 (parts + norm were
            // all published >=1 barrier ago)
            if ((ph & 1) == 0 && h == 2 && ph >= 2) {
                const int r = (ph - 2) >> 1, pj = r & 1;
                const float total = (accp[pj][0][q] + accp[pj][1][q]) +
                                    (accp[pj][2][q] + accp[pj][3][q]);
                const float n2 =
                    ((nshp[pj][0] + nshp[pj][1]) + (nshp[pj][2] + nshp[pj][3])) +
                    ((nshp[pj][4] + nshp[pj][5]) + (nshp[pj][6] + nshp[pj][7]));
                const float inv = 1.0f / ((sqrtf(n2) + kEPS) * (16.0f + kEPS));
                simq[r] = total * inv;
            }

            // matching-half waves gather 64 rotated conflict-free elements
            if ((ph & 1) == (h >> 1)) {
                const char* tb = reinterpret_cast<const char*>(tile[ph & 1]);
                float a[8];
                #pragma unroll
                for (int i = 0; i < 8; ++i) a[i] = 0.f;
                #pragma unroll
                for (int g = 0; g < 64; ++g)
                    a[g & 7] += *reinterpret_cast<const float*>(tb + adr[g]);
                accp[(ph >> 1) & 1][h][q] =
                    ((a[0] + a[1]) + (a[2] + a[3])) +
                    ((a[4] + a[5]) + (a[6] + a[7]));
            }
            BARRIER_LG();
        }
        // tail: finalize the last row
        if (h == 2) {
            const int r = kGens - 1, pj = r & 1;
            const float total = (accp[pj][0][q] + accp[pj][1][q]) +
                                (accp[pj][2][q] + accp[pj][3][q]);
            const float n2 =
                ((nshp[pj][0] + nshp[pj][1]) + (nshp[pj][2] + nshp[pj][3])) +
                ((nshp[pj][4] + nshp[pj][5]) + (nshp[pj][6] + nshp[pj][7]));
            const float inv = 1.0f / ((sqrtf(n2) + kEPS) * (16.0f + kEPS));
            simq[r] = total * inv;
        }
    }
}

// ---------------------------------------------------------------------------
// Phase 2: per-query argmax over 8192 (first-max tie-break = lowest index),
// predictions = float(db_classes[argmax]), unit_sim = max.
// ---------------------------------------------------------------------------
__global__ void argmax_kernel(const float* __restrict__ sims,
                              const int* __restrict__ db_classes,
                              float* __restrict__ preds,
                              float* __restrict__ unit) {
    const int q = blockIdx.x;
    const int t = threadIdx.x;
    const float* row = sims + (size_t)q * kNDB;

    float best = -1e30f;
    int bidx = kNDB;
    for (int n = t; n < kNDB; n += 256) {   // increasing n: '>' keeps first max
        const float v = row[n];
        if (v > best) { best = v; bidx = n; }
    }

    __shared__ float bv[256];
    __shared__ int   bi[256];
    bv[t] = best;
    bi[t] = bidx;
    __syncthreads();
    for (int s2 = 128; s2 > 0; s2 >>= 1) {
        if (t < s2) {
            const float ov = bv[t + s2];
            const int   oi = bi[t + s2];
            if (ov > bv[t] || (ov == bv[t] && oi < bi[t])) {
                bv[t] = ov;
                bi[t] = oi;
            }
        }
        __syncthreads();
    }
    if (t == 0) {
        preds[q] = (float)db_classes[bi[0]];
        unit[q]  = bv[0];
    }
}

// ---------------------------------------------------------------------------
extern "C" void kernel_launch(void* const* d_in, const int* in_sizes, int n_in,
                              void* d_out, int out_size, void* d_ws, size_t ws_size,
                              hipStream_t stream) {
    const int*   seq        = (const int*)d_in[0];     // (8, 1024) int32
    const int*   kp         = (const int*)d_in[1];     // (8, 17)   int32
    const float* db         = (const float*)d_in[2];   // (8192, 128, 256) f32
    const int*   db_classes = (const int*)d_in[3];     // (8192,)   int32

    float* out   = (float*)d_out;                 // sims | preds | unit_sim
    float* preds = out + (size_t)kNQ * kNDB;      // + 1048576
    float* unit  = preds + kNQ;                   // + 128

    uint32_t* table = (uint32_t*)d_ws;            // 128 KiB addr table

    build_table_kernel<<<kNQ, kL2, 0, stream>>>(seq, kp, table);
    sim_kernel<<<kGrid, 1024, 0, stream>>>(db, table, out);
    argmax_kernel<<<kNQ, 256, 0, stream>>>(out, db_classes, preds, unit);
}